// Round 3
// baseline (490.819 us; speedup 1.0000x reference)
//
#include <hip/hip_runtime.h>

// 2-layer LSTM (HID=10), B=2048, T=1024 main + F=64 future steps.
//
// Round 10: r9 (element-pair DLP, LDS h-broadcast) + LDS ordering fix.
// r9 failed at absmax 3.6e-3 (~59 bf16 ulps; passing kernels are 1 ulp):
// the LDS write->read round-trip used mixed pointer types (v2f store,
// float4 class load) with no ordering token -> compiler may hoist the
// broadcast ds_reads above the h-store (stale h by one step; bounded
// contractive error matches the signature). Fix:
//  a) uniform ext_vector types (v2f store, v4f load) for all LDS access
//  b) asm volatile("s_waitcnt lgkmcnt(0)" ::: "memory") between store and
//     broadcast load: memory clobber pins compiler order, lgkmcnt(0)
//     guarantees the RAW at HW level.
// Math unchanged from r9 (algebraically identical to passing r7).
// DS ops: 26/elem-step (r7) -> 12/elem-step here.

#define NB 1024
#define TMAIN 1024
#define HID 10

typedef float v2f __attribute__((ext_vector_type(2)));
typedef float v4f __attribute__((ext_vector_type(4)));

#define PIN2(v) asm volatile("" : "+v"(v))
// pin compiler order around the LDS RAW + guarantee write completion
#define LDS_RAW_FENCE() asm volatile("s_waitcnt lgkmcnt(0)" ::: "memory")

__device__ __forceinline__ float rcp_(float v)  { return __builtin_amdgcn_rcpf(v); }
__device__ __forceinline__ float exp2_(float v) { return __builtin_amdgcn_exp2f(v); }
__device__ __forceinline__ v2f mk2(float x, float y) { v2f r; r.x = x; r.y = y; return r; }
__device__ __forceinline__ v2f pfma(v2f a, v2f b, v2f c) { return __builtin_elementwise_fma(a, b, c); }

__global__ __launch_bounds__(64)
void lstm2_kernel(
    const float* __restrict__ x,
    const float* __restrict__ Wih1, const float* __restrict__ Whh1,
    const float* __restrict__ bih1, const float* __restrict__ bhh1,
    const float* __restrict__ Wih2, const float* __restrict__ Whh2,
    const float* __restrict__ bih2, const float* __restrict__ bhh2,
    const float* __restrict__ Wlin, const float* __restrict__ blin,
    const int* __restrict__ futp,
    float* __restrict__ out)
{
    const int lane = threadIdx.x;
    const int geA  = blockIdx.x * 2;
    const int geB  = geA + 1;
    const int F    = futp[0];
    const int OUTW = TMAIN + F;

    __shared__ __align__(16) float hb1[2 * HID + 4];   // h1 pairs (hA[j],hB[j])
    __shared__ __align__(16) float hb2[2 * HID + 4];   // h2 pairs

    const int L = (lane < 40) ? lane : 0;
    const int k = L / HID;
    const int u = L - k * HID;

    const bool isg = (k == 2);
    const float aK = isg ?  2.8853900817779268f : -1.4426950408889634f;
    const float tK = 2.8853900817779268f;
    // g-gate act pre-scaled by tK: cell states carry tK*c, so ctanh needs no mul
    const v2f aA2 = isg ? mk2(tK, tK)            : mk2(0.f, 0.f);
    const v2f aB2 = isg ? mk2(-2.f*tK, -2.f*tK)  : mk2(1.f, 1.f);

    // ---- per-lane weights (row L), prescaled by aK, SPLAT v2f (same for A,B) ----
    v2f whh1s[10], wih2s[10], whh2s[10], wlins[10];
    #pragma unroll
    for (int j = 0; j < HID; ++j) {
        float w1 = Whh1[L * HID + j] * aK;
        float w2 = Wih2[L * HID + j] * aK;
        float w3 = Whh2[L * HID + j] * aK;
        float wl = Wlin[j];
        whh1s[j] = mk2(w1, w1);
        wih2s[j] = mk2(w2, w2);
        whh2s[j] = mk2(w3, w3);
        wlins[j] = mk2(wl, wl);
    }
    float w0 = Wih1[L] * aK;
    float s1 = (bih1[L] + bhh1[L]) * aK;
    float s2 = (bih2[L] + bhh2[L]) * aK;
    v2f wih1s = mk2(w0, w0);
    v2f b1s   = mk2(s1, s1);
    v2f b2s   = mk2(s2, s2);
    v2f bls   = mk2(blin[0], blin[0]);

    #pragma unroll
    for (int j = 0; j < HID; ++j) { PIN2(whh1s[j]); PIN2(wih2s[j]); PIN2(whh2s[j]); PIN2(wlins[j]); }
    PIN2(wih1s); PIN2(b1s); PIN2(b2s); PIN2(bls);

    const int adr_f = (1 * HID + u) * 4;
    const int adr_g = (2 * HID + u) * 4;
    const int adr_o = (3 * HID + u) * 4;

    auto bp = [](int addr, float v) -> float {
        return __int_as_float(__builtin_amdgcn_ds_bpermute(addr, __float_as_int(v)));
    };
    auto gat = [&](int addr, v2f a) -> v2f {     // gather one gate's act pair
        return mk2(bp(addr, a.x), bp(addr, a.y));
    };
    auto actf2 = [&](v2f p) -> v2f {             // sigma (or tK*tanh on g-lanes)
        v2f q;
        q.x = rcp_(1.0f + exp2_(p.x));
        q.y = rcp_(1.0f + exp2_(p.y));
        return pfma(aB2, q, aA2);
    };
    auto ctanh2 = [&](v2f cs) -> v2f {           // tanh of (pre-scaled) cell state
        v2f q;
        q.x = rcp_(1.0f + exp2_(cs.x));
        q.y = rcp_(1.0f + exp2_(cs.y));
        return pfma(mk2(-2.f, -2.f), q, mk2(1.f, 1.f));
    };

    // ---- state: c pairs on lanes 0..9 (scaled by tK); h pairs in regs ----
    v2f c1 = mk2(0.f, 0.f), c2 = mk2(0.f, 0.f);
    v2f h1p[10], h2p[10];
    #pragma unroll
    for (int j = 0; j < HID; ++j) { h1p[j] = mk2(0.f, 0.f); h2p[j] = mk2(0.f, 0.f); }

    // broadcast reload: 5 uniform-address ds_read_b128 per buffer
    auto load10 = [&](const float* hb, v2f* hp) {
        const v4f* hq = (const v4f*)hb;
        v4f q0 = hq[0];
        v4f q1 = hq[1];
        v4f q2 = hq[2];
        v4f q3 = hq[3];
        v4f q4 = hq[4];
        hp[0] = mk2(q0.x, q0.y); hp[1] = mk2(q0.z, q0.w);
        hp[2] = mk2(q1.x, q1.y); hp[3] = mk2(q1.z, q1.w);
        hp[4] = mk2(q2.x, q2.y); hp[5] = mk2(q2.z, q2.w);
        hp[6] = mk2(q3.x, q3.y); hp[7] = mk2(q3.z, q3.w);
        hp[8] = mk2(q4.x, q4.y); hp[9] = mk2(q4.z, q4.w);
    };
    auto dot10 = [&](const v2f* w, const v2f* h, v2f init) -> v2f {
        v2f A = pfma(h[0], w[0], init);
        v2f B = h[5] * w[5];
        #pragma unroll
        for (int j = 1; j < 5; ++j) {
            A = pfma(h[j], w[j], A);
            B = pfma(h[j + 5], w[j + 5], B);
        }
        return A + B;
    };

    // Pipelined iteration t: cell2(t) and cell1(t+1) as parallel chains.
    auto pipe_iter = [&](v2f xn) -> v2f {
        v2f U = dot10(wih2s, h1p, b2s);
        v2f V = dot10(whh2s, h2p, mk2(0.f, 0.f));
        v2f A = dot10(whh1s, h1p, pfma(wih1s, xn, b1s));
        v2f act2 = actf2(U + V);
        v2f act1 = actf2(A);
        v2f f2 = gat(adr_f, act2), g2 = gat(adr_g, act2), o2 = gat(adr_o, act2);
        v2f f1 = gat(adr_f, act1), g1 = gat(adr_g, act1), o1 = gat(adr_o, act1);
        c2 = pfma(f2, c2, act2 * g2);            // lanes 0..9: act == i-gate
        c1 = pfma(f1, c1, act1 * g1);
        v2f h2u = o2 * ctanh2(c2);
        v2f h1u = o1 * ctanh2(c1);
        if (lane < HID) { ((v2f*)hb1)[lane] = h1u; ((v2f*)hb2)[lane] = h2u; }
        LDS_RAW_FENCE();
        load10(hb1, h1p);
        load10(hb2, h2p);
        return dot10(wlins, h2p, bls);           // head: y pair, no reduce
    };

    auto cell2_only = [&]() -> v2f {
        v2f U = dot10(wih2s, h1p, b2s);
        v2f V = dot10(whh2s, h2p, mk2(0.f, 0.f));
        v2f act2 = actf2(U + V);
        v2f f2 = gat(adr_f, act2), g2 = gat(adr_g, act2), o2 = gat(adr_o, act2);
        c2 = pfma(f2, c2, act2 * g2);
        v2f h2u = o2 * ctanh2(c2);
        if (lane < HID) ((v2f*)hb2)[lane] = h2u;
        LDS_RAW_FENCE();
        load10(hb2, h2p);
        return dot10(wlins, h2p, bls);
    };

    auto fstep = [&](v2f yt) -> v2f {            // serial step for future loop
        v2f A = dot10(whh1s, h1p, pfma(wih1s, yt, b1s));
        v2f act1 = actf2(A);
        v2f f1 = gat(adr_f, act1), g1 = gat(adr_g, act1), o1 = gat(adr_o, act1);
        c1 = pfma(f1, c1, act1 * g1);
        v2f h1u = o1 * ctanh2(c1);
        if (lane < HID) ((v2f*)hb1)[lane] = h1u;
        LDS_RAW_FENCE();
        load10(hb1, h1p);
        return cell2_only();
    };

    // ---- prologue: h1(0), c1(0) from x[0] of both elements ----
    const float4* xrowA = (const float4*)(x + (size_t)geA * TMAIN);
    const float4* xrowB = (const float4*)(x + (size_t)geB * TMAIN);
    float4* orowA = (float4*)(out + (size_t)geA * OUTW);   // OUTW=1088, 16B-aligned
    float4* orowB = (float4*)(out + (size_t)geB * OUTW);
    float4 xvA = xrowA[0];
    float4 xvB = xrowB[0];
    {
        v2f act1 = actf2(pfma(wih1s, mk2(xvA.x, xvB.x), b1s));
        v2f g1 = gat(adr_g, act1), o1 = gat(adr_o, act1);
        c1 = act1 * g1;                                   // c1_old == 0
        v2f h1u = o1 * ctanh2(c1);
        if (lane < HID) ((v2f*)hb1)[lane] = h1u;
        LDS_RAW_FENCE();
        load10(hb1, h1p);
    }

    // ---- main loop: 255 groups of 4 pipelined iterations ----
    #pragma unroll 1
    for (int t4 = 0; t4 < TMAIN / 4 - 1; ++t4) {
        float4 xnA = xrowA[t4 + 1];
        float4 xnB = xrowB[t4 + 1];
        v2f y0 = pipe_iter(mk2(xvA.y, xvB.y));
        v2f y1 = pipe_iter(mk2(xvA.z, xvB.z));
        v2f y2 = pipe_iter(mk2(xvA.w, xvB.w));
        v2f y3 = pipe_iter(mk2(xnA.x, xnB.x));
        if (lane == 0) {
            orowA[t4] = make_float4(y0.x, y1.x, y2.x, y3.x);
            orowB[t4] = make_float4(y0.y, y1.y, y2.y, y3.y);
        }
        xvA = xnA; xvB = xnB;
    }
    {
        v2f y0 = pipe_iter(mk2(xvA.y, xvB.y));
        v2f y1 = pipe_iter(mk2(xvA.z, xvB.z));
        v2f y2 = pipe_iter(mk2(xvA.w, xvB.w));
        v2f y3 = cell2_only();
        if (lane == 0) {
            orowA[TMAIN / 4 - 1] = make_float4(y0.x, y1.x, y2.x, y3.x);
            orowB[TMAIN / 4 - 1] = make_float4(y0.y, y1.y, y2.y, y3.y);
        }
    }

    // ---- future loop: serial (y pair feeds back; uniform on all lanes) ----
    v2f yprev = dot10(wlins, h2p, bls);
    int t = 0;
    #pragma unroll 1
    for (; t + 3 < F; t += 4) {
        v2f y0 = fstep(yprev);
        v2f y1 = fstep(y0);
        v2f y2 = fstep(y1);
        v2f y3 = fstep(y2);
        if (lane == 0) {
            orowA[(TMAIN + t) / 4] = make_float4(y0.x, y1.x, y2.x, y3.x);
            orowB[(TMAIN + t) / 4] = make_float4(y0.y, y1.y, y2.y, y3.y);
        }
        yprev = y3;
    }
    #pragma unroll 1
    for (; t < F; ++t) {
        yprev = fstep(yprev);
        if (lane == 0) {
            out[(size_t)geA * OUTW + TMAIN + t] = yprev.x;
            out[(size_t)geB * OUTW + TMAIN + t] = yprev.y;
        }
    }
}

extern "C" void kernel_launch(void* const* d_in, const int* in_sizes, int n_in,
                              void* d_out, int out_size, void* d_ws, size_t ws_size,
                              hipStream_t stream) {
    const float* x    = (const float*)d_in[0];
    const float* Wih1 = (const float*)d_in[1];
    const float* Whh1 = (const float*)d_in[2];
    const float* bih1 = (const float*)d_in[3];
    const float* bhh1 = (const float*)d_in[4];
    const float* Wih2 = (const float*)d_in[5];
    const float* Whh2 = (const float*)d_in[6];
    const float* bih2 = (const float*)d_in[7];
    const float* bhh2 = (const float*)d_in[8];
    const float* Wlin = (const float*)d_in[9];
    const float* blin = (const float*)d_in[10];
    const int*   futp = (const int*)d_in[11];
    float* out = (float*)d_out;

    lstm2_kernel<<<NB, 64, 0, stream>>>(x, Wih1, Whh1, bih1, bhh1,
                                        Wih2, Whh2, bih2, bhh2,
                                        Wlin, blin, futp, out);
}

// Round 4
// 436.958 us; speedup vs baseline: 1.1233x; 1.1233x over previous
//
#include <hip/hip_runtime.h>

// 2-layer LSTM (HID=10), B=2048, T=1024 main + F=64 future steps.
//
// Round 11: DS-latency elimination. r7/r8/r10 post-mortems: wall tracks the
// serial chain, dominated by DS-pipe latency hops (~120cyc: bpermute gather,
// LDS bcast round-trip). r10 (2 serial LDS hops) was SLOWER than r7 (1
// parallel bpermute hop) at far fewer DS ops -> latency, not throughput.
// This round moves all cross-lane traffic to VALU-class ops:
//  - lane = e*32 + r1*16 + u: elem pair in lane halves, gate-pair row r1
//    (r1=0: (i,f) v2f, r1=1: (g,o)), unit u=0..15 (valid <10).
//  - h-broadcast via 15x v_mov_dpp row_ror (~4cyc each, parallel): dot =
//    sum over 16 rotations with per-lane pre-rotated weights (0 for j>=10).
//    Runtime DPP-direction probe picks (u+r) vs (u-r) weight indexing.
//  - gate exchange: ONE ds_swizzle xor-16 hop (0x401F, unambiguous) + 4
//    cndmask. Only DS op left in the chain; head-dot fills its latency.
//  - y uniform within each 32-half: future-loop feedback needs no bcast.
// Math identical to r7 (same prescaled constants/algebra). Zero LDS.

#define NB 1024
#define TMAIN 1024
#define HID 10

typedef float v2f __attribute__((ext_vector_type(2)));

#define PIN2(v) asm volatile("" : "+v"(v))
#define PIN(v)  asm volatile("" : "+v"(v))

__device__ __forceinline__ float rcp_(float v)  { return __builtin_amdgcn_rcpf(v); }
__device__ __forceinline__ float exp2_(float v) { return __builtin_amdgcn_exp2f(v); }
__device__ __forceinline__ v2f mk2(float x, float y) { v2f r; r.x = x; r.y = y; return r; }
__device__ __forceinline__ v2f pfma(v2f a, v2f b, v2f c) { return __builtin_elementwise_fma(a, b, c); }

template<int R>
__device__ __forceinline__ float rorf(float v) {   // DPP row_ror:R (16-lane rows)
    return __int_as_float(__builtin_amdgcn_update_dpp(
        0, __float_as_int(v), 0x120 + R, 0xF, 0xF, true));
}
__device__ __forceinline__ float swz16(float v) {  // value from lane^16 (within 32-half)
    return __int_as_float(__builtin_amdgcn_ds_swizzle(__float_as_int(v), 0x401F));
}
__device__ __forceinline__ void rot16(float h, float* hr) {
    hr[0] = h;
    hr[1]  = rorf<1>(h);  hr[2]  = rorf<2>(h);  hr[3]  = rorf<3>(h);
    hr[4]  = rorf<4>(h);  hr[5]  = rorf<5>(h);  hr[6]  = rorf<6>(h);
    hr[7]  = rorf<7>(h);  hr[8]  = rorf<8>(h);  hr[9]  = rorf<9>(h);
    hr[10] = rorf<10>(h); hr[11] = rorf<11>(h); hr[12] = rorf<12>(h);
    hr[13] = rorf<13>(h); hr[14] = rorf<14>(h); hr[15] = rorf<15>(h);
}

__global__ __launch_bounds__(64)
__attribute__((amdgpu_waves_per_eu(1)))
void lstm2_kernel(
    const float* __restrict__ x,
    const float* __restrict__ Wih1, const float* __restrict__ Whh1,
    const float* __restrict__ bih1, const float* __restrict__ bhh1,
    const float* __restrict__ Wih2, const float* __restrict__ Whh2,
    const float* __restrict__ bih2, const float* __restrict__ bhh2,
    const float* __restrict__ Wlin, const float* __restrict__ blin,
    const int* __restrict__ futp,
    float* __restrict__ out)
{
    const int lane = threadIdx.x;
    const int e    = lane >> 5;          // element within the pair
    const int r1   = (lane >> 4) & 1;    // 0: (i,f)  1: (g,o)
    const int u    = lane & 15;          // unit (valid < 10)
    const int ge   = blockIdx.x * 2 + e;
    const int F    = futp[0];
    const int OUTW = TMAIN + F;

    // ---- DPP direction probe: does row_ror:1 deliver lane u+1 or u-1? ----
    const int rot1 = __builtin_amdgcn_update_dpp(0, u, 0x121, 0xF, 0xF, true);
    const bool dplus = (rot1 == ((u + 1) & 15));   // true: hr[r] = h[(u+r)&15]

    const bool uok = (u < HID);
    const int  uu  = uok ? u : 0;
    const int  gLo = r1 ? 2 : 0;
    const int  gHi = r1 ? 3 : 1;
    const int  Llo = gLo * HID + uu;
    const int  Lhi = gHi * HID + uu;

    const float tK   = 2.8853900817779268f;   // 2*log2(e)
    const float sK   = -1.4426950408889634f;  // -log2(e)
    const float aKlo = r1 ? tK : sK;          // gLo: g uses tanh scaling
    const float aKhi = sK;                    // gHi in {f,o}: sigmoid
    const v2f aA2 = r1 ? mk2(tK, 0.f)       : mk2(0.f, 0.f);
    const v2f aB2 = r1 ? mk2(-2.f*tK, 1.f)  : mk2(1.f, 1.f);

    // ---- per-lane rotated weight tables (term r multiplies h[jr]) ----
    v2f whh1p[16], wih2p[16], whh2p[16];
    float wlr[16];
    #pragma unroll
    for (int r = 0; r < 16; ++r) {
        int jr = (u + (dplus ? r : 16 - r)) & 15;
        int jc = (jr < HID) ? jr : 0;
        float m = (uok && jr < HID) ? 1.f : 0.f;
        whh1p[r] = mk2(m * aKlo * Whh1[Llo*HID + jc], m * aKhi * Whh1[Lhi*HID + jc]);
        wih2p[r] = mk2(m * aKlo * Wih2[Llo*HID + jc], m * aKhi * Wih2[Lhi*HID + jc]);
        whh2p[r] = mk2(m * aKlo * Whh2[Llo*HID + jc], m * aKhi * Whh2[Lhi*HID + jc]);
        wlr[r]   = (jr < HID) ? Wlin[jc] : 0.f;
    }
    const float mu = uok ? 1.f : 0.f;
    v2f b1pk   = mk2(mu * aKlo * (bih1[Llo] + bhh1[Llo]),
                     mu * aKhi * (bih1[Lhi] + bhh1[Lhi]));
    v2f b2pk   = mk2(mu * aKlo * (bih2[Llo] + bhh2[Llo]),
                     mu * aKhi * (bih2[Lhi] + bhh2[Lhi]));
    v2f wih1pk = mk2(mu * aKlo * Wih1[Llo], mu * aKhi * Wih1[Lhi]);
    float bl = blin[0];

    #pragma unroll
    for (int r = 0; r < 16; ++r) { PIN2(whh1p[r]); PIN2(wih2p[r]); PIN2(whh2p[r]); PIN(wlr[r]); }
    PIN2(b1pk); PIN2(b2pk); PIN2(wih1pk); PIN(bl);

    auto actf2 = [&](v2f p) -> v2f {             // sigma (or tK*tanh on g slot)
        v2f q;
        q.x = rcp_(1.0f + exp2_(p.x));
        q.y = rcp_(1.0f + exp2_(p.y));
        return pfma(aB2, q, aA2);
    };
    auto ctanh_ = [&](float cs) -> float {       // tanh of (tK-scaled) cell state
        return fmaf(-2.0f, rcp_(1.0f + exp2_(cs)), 1.0f);
    };

    // ---- state (per lane; redundant across the 4 row-copies) ----
    float c1 = 0.f, c2 = 0.f, h1 = 0.f, h2 = 0.f;
    float h1r[16], h2r[16];
    #pragma unroll
    for (int r = 0; r < 16; ++r) { h1r[r] = 0.f; h2r[r] = 0.f; }

    // gate exchange: one xor-16 swizzle hop + 4 cndmask
    auto gates = [&](v2f a, float& gi, float& gf, float& gg, float& go) {
        float ox = swz16(a.x);
        float oy = swz16(a.y);
        gi = r1 ? ox  : a.x;
        gf = r1 ? oy  : a.y;
        gg = r1 ? a.x : ox;
        go = r1 ? a.y : oy;
    };
    auto head_ = [&]() -> float {                // y from h2 rotations (all lanes)
        float Y = fmaf(wlr[0], h2r[0], bl);
        float Z = wlr[1] * h2r[1];
        #pragma unroll
        for (int r = 2; r < 16; r += 2) {
            Y = fmaf(wlr[r],     h2r[r],     Y);
            Z = fmaf(wlr[r + 1], h2r[r + 1], Z);
        }
        return Y + Z;
    };
    auto dot16 = [&](const v2f* wp, const float* hr, v2f init) -> v2f {
        v2f P = init;
        v2f Q = wp[1] * mk2(hr[1], hr[1]);
        #pragma unroll
        for (int r = 2; r < 16; r += 2) {
            P = pfma(wp[r],     mk2(hr[r],     hr[r]),     P);
            Q = pfma(wp[r + 1], mk2(hr[r + 1], hr[r + 1]), Q);
        }
        return pfma(wp[0], mk2(hr[0], hr[0]), P) + Q;
    };

    auto cell2head = [&]() -> float {            // cell2 from h1r/h2r, then y
        v2f P = dot16(wih2p, h1r, b2pk);
        v2f Q = whh2p[1] * mk2(h2r[1], h2r[1]);
        #pragma unroll
        for (int r = 2; r < 16; r += 2) {
            P = pfma(whh2p[r],     mk2(h2r[r],     h2r[r]),     P);
            Q = pfma(whh2p[r + 1], mk2(h2r[r + 1], h2r[r + 1]), Q);
        }
        P = pfma(whh2p[0], mk2(h2r[0], h2r[0]), P);
        v2f a2 = actf2(P + Q);
        float i2, f2, g2, o2; gates(a2, i2, f2, g2, o2);
        c2 = fmaf(f2, c2, i2 * g2);
        h2 = o2 * ctanh_(c2);
        rot16(h2, h2r);
        return head_();
    };

    // Pipelined iteration: cell2(t) and cell1(t+1) as parallel chains.
    auto pipe_iter = [&](float xn) -> float {
        v2f P = dot16(wih2p, h1r, b2pk);                       // pre2 part 1
        v2f Q = whh2p[1] * mk2(h2r[1], h2r[1]);
        #pragma unroll
        for (int r = 2; r < 16; r += 2) {
            P = pfma(whh2p[r],     mk2(h2r[r],     h2r[r]),     P);
            Q = pfma(whh2p[r + 1], mk2(h2r[r + 1], h2r[r + 1]), Q);
        }
        P = pfma(whh2p[0], mk2(h2r[0], h2r[0]), P);
        v2f A = dot16(whh1p, h1r, pfma(wih1pk, mk2(xn, xn), b1pk));  // pre1
        v2f a2 = actf2(P + Q);
        v2f a1 = actf2(A);
        float i2, f2, g2, o2; gates(a2, i2, f2, g2, o2);
        float i1, f1, g1, o1; gates(a1, i1, f1, g1, o1);
        c2 = fmaf(f2, c2, i2 * g2);
        c1 = fmaf(f1, c1, i1 * g1);
        float h2n = o2 * ctanh_(c2);
        float h1n = o1 * ctanh_(c1);
        h2 = h2n; h1 = h1n;
        rot16(h2n, h2r);
        rot16(h1n, h1r);
        return head_();
    };

    auto fstep = [&](float yt) -> float {        // serial future step
        v2f A = dot16(whh1p, h1r, pfma(wih1pk, mk2(yt, yt), b1pk));
        v2f a1 = actf2(A);
        float i1, f1, g1, o1; gates(a1, i1, f1, g1, o1);
        c1 = fmaf(f1, c1, i1 * g1);
        h1 = o1 * ctanh_(c1);
        rot16(h1, h1r);
        return cell2head();
    };

    // ---- prologue: h1(0), c1(0) from x[0] ----
    const float4* xrow = (const float4*)(x + (size_t)ge * TMAIN);
    float4* orow = (float4*)(out + (size_t)ge * OUTW);   // OUTW=1088, 16B rows
    float4 xv = xrow[0];
    {
        v2f a1 = actf2(pfma(wih1pk, mk2(xv.x, xv.x), b1pk));
        float i1, f1, g1, o1; gates(a1, i1, f1, g1, o1);
        c1 = i1 * g1;                                    // c1_old == 0
        h1 = o1 * ctanh_(c1);
        rot16(h1, h1r);
    }

    // ---- main loop: 255 groups of 4 pipelined iterations ----
    #pragma unroll 1
    for (int t4 = 0; t4 < TMAIN / 4 - 1; ++t4) {
        float4 xn = xrow[t4 + 1];
        float y0 = pipe_iter(xv.y);
        float y1 = pipe_iter(xv.z);
        float y2 = pipe_iter(xv.w);
        float y3 = pipe_iter(xn.x);
        if ((lane & 31) == 0) orow[t4] = make_float4(y0, y1, y2, y3);
        xv = xn;
    }
    {
        float y0 = pipe_iter(xv.y);
        float y1 = pipe_iter(xv.z);
        float y2 = pipe_iter(xv.w);
        float y3 = cell2head();
        if ((lane & 31) == 0) orow[TMAIN / 4 - 1] = make_float4(y0, y1, y2, y3);
    }

    // ---- future loop: serial; y uniform within each 32-half ----
    float yprev = head_();
    int t = 0;
    #pragma unroll 1
    for (; t + 3 < F; t += 4) {
        float y0 = fstep(yprev);
        float y1 = fstep(y0);
        float y2 = fstep(y1);
        float y3 = fstep(y2);
        if ((lane & 31) == 0) orow[(TMAIN + t) / 4] = make_float4(y0, y1, y2, y3);
        yprev = y3;
    }
    #pragma unroll 1
    for (; t < F; ++t) {
        yprev = fstep(yprev);
        if ((lane & 31) == 0) out[(size_t)ge * OUTW + TMAIN + t] = yprev;
    }
}

extern "C" void kernel_launch(void* const* d_in, const int* in_sizes, int n_in,
                              void* d_out, int out_size, void* d_ws, size_t ws_size,
                              hipStream_t stream) {
    const float* x    = (const float*)d_in[0];
    const float* Wih1 = (const float*)d_in[1];
    const float* Whh1 = (const float*)d_in[2];
    const float* bih1 = (const float*)d_in[3];
    const float* bhh1 = (const float*)d_in[4];
    const float* Wih2 = (const float*)d_in[5];
    const float* Whh2 = (const float*)d_in[6];
    const float* bih2 = (const float*)d_in[7];
    const float* bhh2 = (const float*)d_in[8];
    const float* Wlin = (const float*)d_in[9];
    const float* blin = (const float*)d_in[10];
    const int*   futp = (const int*)d_in[11];
    float* out = (float*)d_out;

    lstm2_kernel<<<NB, 64, 0, stream>>>(x, Wih1, Whh1, bih1, bhh1,
                                        Wih2, Whh2, bih2, bhh2,
                                        Wlin, blin, futp, out);
}

// Round 5
// 395.393 us; speedup vs baseline: 1.2413x; 1.1051x over previous
//
#include <hip/hip_runtime.h>

// 2-layer LSTM (HID=10), B=2048, T=1024 main + F=64 future steps.
//
// Round 12: padding-free dots via pair-aware ds_swizzle broadcast.
// Empirical law from r7/r8/r10/r11: wall tracks VALU *execution* cycles per
// element (busy/elem pinned ~320cyc, VALUBusy ~73%, across DS-heavy, DPP-heavy,
// 1/2/4-wave variants). So: cut executed VALU work.
//  - r11's DPP-16 rotation ring forced 16-term dots (6/16 zero padding) and
//    30 v_mov_dpp per step. Replace with ds_swizzle BitMode (and=0,or=j):
//    broadcasts lane j within each 32-half INDEPENDENTLY (element-pair aware),
//    register-flow only (no LDS storage, no ordering hazard).
//  - dots: 48 pk_fma -> 31 (10 terms, no padding); head: 16 -> 10 fma;
//    rot16 (30 DPP, VALU pipe) -> 20 swz (DS pipe, off the critical resource).
//  - drops rotated weight tables + DPP-direction probe (VGPR 160 -> ~120).
// Layout unchanged from r11: lane = e*32 + r1*16 + u; r1=0 holds (i,f),
// r1=1 holds (g,o); gate exchange via one xor-16 swizzle + cndmask.
// Math identical to r7/r11 (same prescaled constants). Zero LDS.

#define NB 1024
#define TMAIN 1024
#define HID 10

typedef float v2f __attribute__((ext_vector_type(2)));

#define PIN2(v) asm volatile("" : "+v"(v))
#define PIN(v)  asm volatile("" : "+v"(v))

__device__ __forceinline__ float rcp_(float v)  { return __builtin_amdgcn_rcpf(v); }
__device__ __forceinline__ float exp2_(float v) { return __builtin_amdgcn_exp2f(v); }
__device__ __forceinline__ v2f mk2(float x, float y) { v2f r; r.x = x; r.y = y; return r; }
__device__ __forceinline__ v2f pfma(v2f a, v2f b, v2f c) { return __builtin_elementwise_fma(a, b, c); }

template<int J>
__device__ __forceinline__ float bc32(float v) {   // broadcast lane J within each 32-half
    return __int_as_float(__builtin_amdgcn_ds_swizzle(__float_as_int(v), (J << 5)));
}
__device__ __forceinline__ float swz16(float v) {  // value from lane^16 (within 32-half)
    return __int_as_float(__builtin_amdgcn_ds_swizzle(__float_as_int(v), 0x401F));
}
__device__ __forceinline__ void bcast10(float h, float* hb) {
    hb[0] = bc32<0>(h); hb[1] = bc32<1>(h); hb[2] = bc32<2>(h); hb[3] = bc32<3>(h);
    hb[4] = bc32<4>(h); hb[5] = bc32<5>(h); hb[6] = bc32<6>(h); hb[7] = bc32<7>(h);
    hb[8] = bc32<8>(h); hb[9] = bc32<9>(h);
}

__global__ __launch_bounds__(64)
__attribute__((amdgpu_waves_per_eu(1)))
void lstm2_kernel(
    const float* __restrict__ x,
    const float* __restrict__ Wih1, const float* __restrict__ Whh1,
    const float* __restrict__ bih1, const float* __restrict__ bhh1,
    const float* __restrict__ Wih2, const float* __restrict__ Whh2,
    const float* __restrict__ bih2, const float* __restrict__ bhh2,
    const float* __restrict__ Wlin, const float* __restrict__ blin,
    const int* __restrict__ futp,
    float* __restrict__ out)
{
    const int lane = threadIdx.x;
    const int e    = lane >> 5;          // element within the pair
    const int r1   = (lane >> 4) & 1;    // 0: (i,f)  1: (g,o)
    const int u    = lane & 15;          // unit (valid < 10)
    const int ge   = blockIdx.x * 2 + e;
    const int F    = futp[0];
    const int OUTW = TMAIN + F;

    const bool uok = (u < HID);
    const int  uu  = uok ? u : 0;
    const int  Llo = (r1 ? 2 : 0) * HID + uu;    // i or g row
    const int  Lhi = (r1 ? 3 : 1) * HID + uu;    // f or o row

    const float tK   = 2.8853900817779268f;   // 2*log2(e)
    const float sK   = -1.4426950408889634f;  // -log2(e)
    const float aKlo = r1 ? tK : sK;          // g uses tanh scaling
    const float aKhi = sK;                    // f/o: sigmoid
    const v2f aA2 = r1 ? mk2(tK, 0.f)       : mk2(0.f, 0.f);
    const v2f aB2 = r1 ? mk2(-2.f*tK, 1.f)  : mk2(1.f, 1.f);

    // ---- per-lane weight rows (gate-pair packed), prescaled; masked if u>=10 ----
    const float mu = uok ? 1.f : 0.f;
    v2f whh1p[10], wih2p[10], whh2p[10];
    float wl[10];
    #pragma unroll
    for (int j = 0; j < HID; ++j) {
        whh1p[j] = mk2(mu * aKlo * Whh1[Llo*HID + j], mu * aKhi * Whh1[Lhi*HID + j]);
        wih2p[j] = mk2(mu * aKlo * Wih2[Llo*HID + j], mu * aKhi * Wih2[Lhi*HID + j]);
        whh2p[j] = mk2(mu * aKlo * Whh2[Llo*HID + j], mu * aKhi * Whh2[Lhi*HID + j]);
        wl[j]    = Wlin[j];
    }
    v2f b1pk   = mk2(mu * aKlo * (bih1[Llo] + bhh1[Llo]),
                     mu * aKhi * (bih1[Lhi] + bhh1[Lhi]));
    v2f b2pk   = mk2(mu * aKlo * (bih2[Llo] + bhh2[Llo]),
                     mu * aKhi * (bih2[Lhi] + bhh2[Lhi]));
    v2f wih1pk = mk2(mu * aKlo * Wih1[Llo], mu * aKhi * Wih1[Lhi]);
    float bl = blin[0];

    #pragma unroll
    for (int j = 0; j < HID; ++j) { PIN2(whh1p[j]); PIN2(wih2p[j]); PIN2(whh2p[j]); PIN(wl[j]); }
    PIN2(b1pk); PIN2(b2pk); PIN2(wih1pk); PIN(bl);

    auto actf2 = [&](v2f p) -> v2f {             // sigma (or tK*tanh on g slot)
        v2f q;
        q.x = rcp_(1.0f + exp2_(p.x));
        q.y = rcp_(1.0f + exp2_(p.y));
        return pfma(aB2, q, aA2);
    };
    auto ctanh_ = [&](float cs) -> float {       // tanh of (tK-scaled) cell state
        return fmaf(-2.0f, rcp_(1.0f + exp2_(cs)), 1.0f);
    };

    // ---- state (per lane; redundant across r1 rows) ----
    float c1 = 0.f, c2 = 0.f;
    float h1b[10], h2b[10];                      // broadcast h vectors (per 32-half)
    #pragma unroll
    for (int j = 0; j < HID; ++j) { h1b[j] = 0.f; h2b[j] = 0.f; }

    // gate exchange: one xor-16 swizzle hop + 4 cndmask
    auto gates = [&](v2f a, float& gi, float& gf, float& gg, float& go) {
        float ox = swz16(a.x);
        float oy = swz16(a.y);
        gi = r1 ? ox  : a.x;
        gf = r1 ? oy  : a.y;
        gg = r1 ? a.x : ox;
        go = r1 ? a.y : oy;
    };
    auto dot10p = [&](const v2f* w, const float* hb, v2f init) -> v2f {
        v2f P = pfma(w[0], mk2(hb[0], hb[0]), init);
        v2f Q = w[1] * mk2(hb[1], hb[1]);
        #pragma unroll
        for (int j = 2; j < HID; j += 2) {
            P = pfma(w[j],     mk2(hb[j],     hb[j]),     P);
            Q = pfma(w[j + 1], mk2(hb[j + 1], hb[j + 1]), Q);
        }
        return P + Q;
    };
    auto head_ = [&]() -> float {                // y from h2 broadcast (all lanes)
        float Y = fmaf(wl[0], h2b[0], bl);
        float Z = wl[1] * h2b[1];
        #pragma unroll
        for (int j = 2; j < HID; j += 2) {
            Y = fmaf(wl[j],     h2b[j],     Y);
            Z = fmaf(wl[j + 1], h2b[j + 1], Z);
        }
        return Y + Z;
    };

    auto cell2head = [&]() -> float {            // cell2 from h1b/h2b, then y
        v2f U = dot10p(wih2p, h1b, b2pk);
        v2f V = dot10p(whh2p, h2b, mk2(0.f, 0.f));
        v2f a2 = actf2(U + V);
        float i2, f2, g2, o2; gates(a2, i2, f2, g2, o2);
        c2 = fmaf(f2, c2, i2 * g2);
        float h2n = o2 * ctanh_(c2);
        bcast10(h2n, h2b);
        return head_();
    };

    // Pipelined iteration: cell2(t) and cell1(t+1) as parallel chains.
    auto pipe_iter = [&](float xn) -> float {
        v2f U = dot10p(wih2p, h1b, b2pk);
        v2f V = dot10p(whh2p, h2b, mk2(0.f, 0.f));
        v2f A = dot10p(whh1p, h1b, pfma(wih1pk, mk2(xn, xn), b1pk));
        v2f a2 = actf2(U + V);
        v2f a1 = actf2(A);
        float i2, f2, g2, o2; gates(a2, i2, f2, g2, o2);
        float i1, f1, g1, o1; gates(a1, i1, f1, g1, o1);
        c2 = fmaf(f2, c2, i2 * g2);
        c1 = fmaf(f1, c1, i1 * g1);
        float h2n = o2 * ctanh_(c2);
        float h1n = o1 * ctanh_(c1);
        bcast10(h2n, h2b);
        bcast10(h1n, h1b);
        return head_();
    };

    auto fstep = [&](float yt) -> float {        // serial future step
        v2f A = dot10p(whh1p, h1b, pfma(wih1pk, mk2(yt, yt), b1pk));
        v2f a1 = actf2(A);
        float i1, f1, g1, o1; gates(a1, i1, f1, g1, o1);
        c1 = fmaf(f1, c1, i1 * g1);
        float h1n = o1 * ctanh_(c1);
        bcast10(h1n, h1b);
        return cell2head();
    };

    // ---- prologue: h1(0), c1(0) from x[0] ----
    const float4* xrow = (const float4*)(x + (size_t)ge * TMAIN);
    float4* orow = (float4*)(out + (size_t)ge * OUTW);   // OUTW=1088, 16B rows
    float4 xv = xrow[0];
    {
        v2f a1 = actf2(pfma(wih1pk, mk2(xv.x, xv.x), b1pk));
        float i1, f1, g1, o1; gates(a1, i1, f1, g1, o1);
        c1 = i1 * g1;                                    // c1_old == 0
        float h1n = o1 * ctanh_(c1);
        bcast10(h1n, h1b);
    }

    // ---- main loop: 255 groups of 4 pipelined iterations ----
    #pragma unroll 1
    for (int t4 = 0; t4 < TMAIN / 4 - 1; ++t4) {
        float4 xn = xrow[t4 + 1];
        float y0 = pipe_iter(xv.y);
        float y1 = pipe_iter(xv.z);
        float y2 = pipe_iter(xv.w);
        float y3 = pipe_iter(xn.x);
        if ((lane & 31) == 0) orow[t4] = make_float4(y0, y1, y2, y3);
        xv = xn;
    }
    {
        float y0 = pipe_iter(xv.y);
        float y1 = pipe_iter(xv.z);
        float y2 = pipe_iter(xv.w);
        float y3 = cell2head();
        if ((lane & 31) == 0) orow[TMAIN / 4 - 1] = make_float4(y0, y1, y2, y3);
    }

    // ---- future loop: serial; y uniform within each 32-half ----
    float yprev = head_();
    int t = 0;
    #pragma unroll 1
    for (; t + 3 < F; t += 4) {
        float y0 = fstep(yprev);
        float y1 = fstep(y0);
        float y2 = fstep(y1);
        float y3 = fstep(y2);
        if ((lane & 31) == 0) orow[(TMAIN + t) / 4] = make_float4(y0, y1, y2, y3);
        yprev = y3;
    }
    #pragma unroll 1
    for (; t < F; ++t) {
        yprev = fstep(yprev);
        if ((lane & 31) == 0) out[(size_t)ge * OUTW + TMAIN + t] = yprev;
    }
}

extern "C" void kernel_launch(void* const* d_in, const int* in_sizes, int n_in,
                              void* d_out, int out_size, void* d_ws, size_t ws_size,
                              hipStream_t stream) {
    const float* x    = (const float*)d_in[0];
    const float* Wih1 = (const float*)d_in[1];
    const float* Whh1 = (const float*)d_in[2];
    const float* bih1 = (const float*)d_in[3];
    const float* bhh1 = (const float*)d_in[4];
    const float* Wih2 = (const float*)d_in[5];
    const float* Whh2 = (const float*)d_in[6];
    const float* bih2 = (const float*)d_in[7];
    const float* bhh2 = (const float*)d_in[8];
    const float* Wlin = (const float*)d_in[9];
    const float* blin = (const float*)d_in[10];
    const int*   futp = (const int*)d_in[11];
    float* out = (float*)d_out;

    lstm2_kernel<<<NB, 64, 0, stream>>>(x, Wih1, Whh1, bih1, bhh1,
                                        Wih2, Whh2, bih2, bhh2,
                                        Wlin, blin, futp, out);
}